// Round 9
// baseline (216.654 us; speedup 1.0000x reference)
//
#include <hip/hip_runtime.h>
#include <cstdint>

typedef short bf16x8 __attribute__((ext_vector_type(8)));
typedef float f32x4  __attribute__((ext_vector_type(4)));

#define TOK    64         // tokens per block
#define CCH    16         // codes per chunk (per wave)
#define NCH    32         // chunks per K-half (512 codes)
#define MAXC   32

__device__ __forceinline__ unsigned short f2bf(float f) {
  unsigned u = __float_as_uint(f);
  return (unsigned short)((u + 0x7FFFu + ((u >> 16) & 1u)) >> 16);
}
__device__ __forceinline__ uint4 pack8(float4 a, float4 b) {
  uint4 u;
  u.x = (unsigned)f2bf(a.x) | ((unsigned)f2bf(a.y) << 16);
  u.y = (unsigned)f2bf(a.z) | ((unsigned)f2bf(a.w) << 16);
  u.z = (unsigned)f2bf(b.x) | ((unsigned)f2bf(b.y) << 16);
  u.w = (unsigned)f2bf(b.z) | ((unsigned)f2bf(b.w) << 16);
  return u;
}
// async global->LDS DMA, 16 B per lane. LDS dest = wave-uniform base + lane*16;
// global src is per-lane. Tracked by the ISSUING WAVE's vmcnt only.
__device__ __forceinline__ void gload16(const unsigned short* g, unsigned short* l) {
  __builtin_amdgcn_global_load_lds(
      (const __attribute__((address_space(1))) unsigned int*)(const void*)g,
      (__attribute__((address_space(3))) unsigned int*)(void*)l, 16, 0, 0);
}

// ---------------------------------------------------------------------------
// Prep: cb_bf = bf16(cb), ee = ||cb_k||^2. Block 0 zeroes global accumulators.
// ---------------------------------------------------------------------------
__global__ __launch_bounds__(256) void vq_prep(const float* __restrict__ cb,
                                               unsigned short* __restrict__ cb_bf,
                                               float* __restrict__ ee,
                                               float* __restrict__ acc2,
                                               int* __restrict__ done_ctr, int K) {
  if (blockIdx.x == 0 && threadIdx.x == 0) {
    acc2[0] = 0.f; acc2[1] = 0.f; *done_ctr = 0;
  }
  int wave = threadIdx.x >> 6, lane = threadIdx.x & 63;
  int k = blockIdx.x * 4 + wave;
  if (k >= K) return;
  float4 v = *reinterpret_cast<const float4*>(cb + (size_t)k * 256 + lane * 4);
  float s = v.x * v.x + v.y * v.y + v.z * v.z + v.w * v.w;
  #pragma unroll
  for (int off = 32; off; off >>= 1) s += __shfl_down(s, off, 64);
  ushort4 b;
  b.x = f2bf(v.x); b.y = f2bf(v.y); b.z = f2bf(v.z); b.w = f2bf(v.w);
  *reinterpret_cast<ushort4*>(cb_bf + (size_t)k * 256 + lane * 4) = b;
  if (lane == 0) ee[k] = s;
}

// ---------------------------------------------------------------------------
// Main: 256 thr (4 waves), TOK=64, grid 512 -> 2 blocks/CU (LDS ~74.6 KB).
// WAVE-PRIVATE ASYNC PIPELINE, ZERO BARRIERS in the main loop.
// Evidence R0-R8: all block-synchronized variants (any staging flavor) hit
// ~106 us with every pipe <20% busy -- waves stall TOGETHER at each chunk
// rendezvous, and 2 waves/SIMD can't cover it. R7 (barrier-free but no LDS)
// showed the compiler won't pipeline global->MFMA directly. This round keeps
// LDS staging (compiler pipelines ds_read->MFMA well) but makes it private:
// wave (p=wv&1, kh=wv>>1) owns tokens [32p,32p+32) x K-half kh, streaming 32
// chunks x 16 codes through its OWN 2x8KB LDS double-buffer via
// global_load_lds, synchronized ONLY by its own counted vmcnt (T4 pattern:
// issue 8 for chunk lc+1, s_waitcnt vmcnt(8) -> chunk lc's 8 have landed).
// Waves drift freely; no rendezvous until one barrier before the epilogue.
// Screen: publish-then-read LDS atomicMin gate (R8-proven; publish first
// avoids the chunk-0 admit-everything blowup). Margin 1.5 + 0.002*zn*en,
// ushort cand MAXC=32, exact fp32 rescore (R5 ILP), exact-scan fallback.
// DO NOT: 512-thread blocks (VGPR crush + spill); __launch_bounds__ 2nd arg
// >2 (R6: crushed to 52 VGPR); register prefetch arrays (R3 spill); MAXC<32
// or looser margin (R2: 4x straggler blowup); gate-read-before-publish on
// chunk 0 (admits all 16 codes -> overflow).
// ---------------------------------------------------------------------------
__global__ __launch_bounds__(256, 2) void vq_main(
    const float* __restrict__ z, const float* __restrict__ cb,
    const unsigned short* __restrict__ cb_bf, const float* __restrict__ ee,
    const float* __restrict__ mask,
    float* __restrict__ out_q, float* __restrict__ out_idx_f,
    float* __restrict__ out_loss, float* __restrict__ acc2,
    int* __restrict__ done_ctr, int nblocks, int K) {
  // 64 KB: first 32 KB doubles as z-stage (rows 0..63); then wave wv owns
  // sbuf[wv*8192 .. wv*8192+8191] = two 16-row (4096-ushort) chunk buffers.
  __shared__ __align__(16) unsigned short sbuf[32768];
  __shared__ float ee_lds[1024];                             // 4 KB
  __shared__ float znorm[TOK];
  __shared__ int   ccnt[TOK];
  __shared__ unsigned umin[TOK];                             // packed float gate
  __shared__ unsigned short cand[TOK * MAXC];                // 4 KB
  __shared__ unsigned short bkbuf[TOK];
  __shared__ float red[8];
  __shared__ bool  last;

  const int t = threadIdx.x;
  const int n0 = blockIdx.x * TOK;
  const int wv = t >> 6, lane = t & 63;
  const int p = wv & 1, kh = wv >> 1;
  const int quad = lane >> 4, l15 = lane & 15;
  const int q16 = t & 15;

  // ---- code norms into LDS ----
  ee_lds[t]       = ee[t];
  ee_lds[t + 256] = ee[t + 256];
  ee_lds[t + 512] = ee[t + 512];
  ee_lds[t + 768] = ee[t + 768];
  if (t < TOK) { ccnt[t] = 0; umin[t] = 0x7F7FFFFFu; }

  // ---- stage z -> bf16 into sbuf rows 0..63 (XOR-swizzled); ||z|| ----
  #pragma unroll
  for (int pass = 0; pass < 4; ++pass) {
    int row = pass * 16 + (t >> 4);
    const float* zr = z + (size_t)(n0 + row) * 256;
    float ssq = 0.f;
    #pragma unroll
    for (int j = 0; j < 2; ++j) {
      float4 a = *reinterpret_cast<const float4*>(zr + q16 * 16 + j * 8);
      float4 b = *reinterpret_cast<const float4*>(zr + q16 * 16 + j * 8 + 4);
      ssq += a.x*a.x + a.y*a.y + a.z*a.z + a.w*a.w
           + b.x*b.x + b.y*b.y + b.z*b.z + b.w*b.w;
      int g = q16 * 2 + j;                       // logical granule 0..31
      *reinterpret_cast<uint4*>(&sbuf[row * 256 + ((g ^ (row & 7)) * 8)]) = pack8(a, b);
    }
    #pragma unroll
    for (int off = 1; off < 16; off <<= 1) ssq += __shfl_xor(ssq, off, 64);
    if (q16 == 0) znorm[row] = sqrtf(ssq);
  }
  __syncthreads();  // S1: z staged, gates/counters initialized

  // ---- A fragments: wave owns token rows p*32 + s*16 + l15 ----
  bf16x8 afrag[2][8];
  float  znreg[2][4];
  #pragma unroll
  for (int s = 0; s < 2; ++s) {
    int row = p * 32 + s * 16 + l15;
    #pragma unroll
    for (int kk = 0; kk < 8; ++kk) {
      int g = (quad + kk * 4) ^ (row & 7);
      afrag[s][kk] = *reinterpret_cast<const bf16x8*>(&sbuf[row * 256 + g * 8]);
    }
    #pragma unroll
    for (int r = 0; r < 4; ++r)
      znreg[s][r] = znorm[p * 32 + s * 16 + quad * 4 + r];
  }
  __syncthreads();  // S2: ALL waves' A-loads done before any DMA overwrites z-stage

  unsigned short* wbuf = &sbuf[wv * 8192];         // this wave's 16 KB region
  const unsigned short* cbh = cb_bf + (size_t)kh * 512 * 256;

  // ---- prologue: issue chunk 0 -> buf0 (own vmcnt, no waits yet) ----
  #pragma unroll
  for (int i = 0; i < 8; ++i) {
    int f = i * 64 + lane;                         // granule 0..511
    int row = f >> 5, slot = f & 31;
    gload16(cbh + (size_t)row * 256 + ((slot ^ (row & 7)) * 8),
            wbuf + (size_t)(i * 64) * 8);
  }

  // ---- chunk loop: 32 chunks x 16 codes, wave-private dbuf, NO barriers ----
  for (int lc = 0; lc < NCH; ++lc) {
    unsigned short* cur = wbuf + (lc & 1) * 4096;
    unsigned short* nxt = wbuf + ((lc + 1) & 1) * 4096;
    if (lc < NCH - 1) {   // issue next chunk's 8 DMAs, then wait for cur's 8
      const unsigned short* base = cbh + (size_t)(lc + 1) * CCH * 256;
      #pragma unroll
      for (int i = 0; i < 8; ++i) {
        int f = i * 64 + lane;
        int row = f >> 5, slot = f & 31;
        gload16(base + (size_t)row * 256 + ((slot ^ (row & 7)) * 8),
                nxt + (size_t)(i * 64) * 8);
      }
      asm volatile("s_waitcnt vmcnt(8)" ::: "memory");  // cur landed; nxt in flight
    } else {
      asm volatile("s_waitcnt vmcnt(0)" ::: "memory");  // last chunk landed
    }

    const int kbase = kh * 512 + lc * CCH;
    float e0 = ee_lds[kbase + l15];

    f32x4 acc[2];
    acc[0] = (f32x4){0.f, 0.f, 0.f, 0.f};
    acc[1] = (f32x4){0.f, 0.f, 0.f, 0.f};
    __builtin_amdgcn_s_setprio(1);
    #pragma unroll
    for (int kk = 0; kk < 8; ++kk) {
      int gph = (quad + kk * 4) ^ (l15 & 7);
      bf16x8 b = *reinterpret_cast<const bf16x8*>(&cur[l15 * 256 + gph * 8]);
      acc[0] = __builtin_amdgcn_mfma_f32_16x16x32_bf16(afrag[0][kk], b, acc[0], 0, 0, 0);
      acc[1] = __builtin_amdgcn_mfma_f32_16x16x32_bf16(afrag[1][kk], b, acc[1], 0, 0, 0);
    }
    __builtin_amdgcn_s_setprio(0);

    float en0 = sqrtf(e0);
    #pragma unroll
    for (int s = 0; s < 2; ++s) {
      #pragma unroll
      for (int r = 0; r < 4; ++r) {
        float d0 = e0 - 2.f * acc[s][r];
        int tok = p * 32 + s * 16 + quad * 4 + r;
        // publish FIRST (same-wave DS in-order -> gate includes these 16
        // lanes), then read; prevents chunk-0 admit-everything overflow.
        atomicMin(&umin[tok], __float_as_uint(fmaxf(d0, 0.f)));
        float am = __uint_as_float(umin[tok]);
        if (d0 <= am + 1.5f + 0.002f * znreg[s][r] * en0) {
          int sl = atomicAdd(&ccnt[tok], 1);
          if (sl < MAXC) cand[tok * MAXC + sl] = (unsigned short)(kbase + l15);
        }
      }
    }
  }
  __syncthreads();  // single rendezvous: cand/ccnt/umin complete

  // ---- phase 1: exact fp32 rescore (candidate loop 4-way unrolled) ----
  for (int it = 0; it < 16; ++it) {
    int tok = wv * 16 + it;
    int n = n0 + tok;
    float4 zv = *reinterpret_cast<const float4*>(z + (size_t)n * 256 + lane * 4);
    int cnt = ccnt[tok];
    float bs = 3.4e38f; int bk = 0;
    if (cnt > MAXC) {  // overflow safety net: exact scan of all K, 2-unrolled
      for (int k = 0; k < K; k += 2) {
        float4 ea = *reinterpret_cast<const float4*>(cb + (size_t)k * 256 + lane * 4);
        float4 eb = *reinterpret_cast<const float4*>(cb + (size_t)(k + 1) * 256 + lane * 4);
        float pa = zv.x * ea.x + zv.y * ea.y + zv.z * ea.z + zv.w * ea.w;
        float pb = zv.x * eb.x + zv.y * eb.y + zv.z * eb.z + zv.w * eb.w;
        #pragma unroll
        for (int off = 32; off; off >>= 1) {
          pa += __shfl_xor(pa, off, 64);
          pb += __shfl_xor(pb, off, 64);
        }
        float sa = ee_lds[k] - 2.f * pa;
        float sb = ee_lds[k + 1] - 2.f * pb;
        if (sa < bs) { bs = sa; bk = k; }
        if (sb < bs) { bs = sb; bk = k + 1; }
      }
    } else {
      int c = 0;
      for (; c + 4 <= cnt; c += 4) {
        int k0 = cand[tok * MAXC + c];
        int k1 = cand[tok * MAXC + c + 1];
        int k2 = cand[tok * MAXC + c + 2];
        int k3 = cand[tok * MAXC + c + 3];
        float4 e0 = *reinterpret_cast<const float4*>(cb + (size_t)k0 * 256 + lane * 4);
        float4 e1 = *reinterpret_cast<const float4*>(cb + (size_t)k1 * 256 + lane * 4);
        float4 e2 = *reinterpret_cast<const float4*>(cb + (size_t)k2 * 256 + lane * 4);
        float4 e3 = *reinterpret_cast<const float4*>(cb + (size_t)k3 * 256 + lane * 4);
        float p0 = zv.x * e0.x + zv.y * e0.y + zv.z * e0.z + zv.w * e0.w;
        float p1 = zv.x * e1.x + zv.y * e1.y + zv.z * e1.z + zv.w * e1.w;
        float p2 = zv.x * e2.x + zv.y * e2.y + zv.z * e2.z + zv.w * e2.w;
        float p3 = zv.x * e3.x + zv.y * e3.y + zv.z * e3.z + zv.w * e3.w;
        #pragma unroll
        for (int off = 32; off; off >>= 1) {   // 4 independent reduce chains
          p0 += __shfl_xor(p0, off, 64);
          p1 += __shfl_xor(p1, off, 64);
          p2 += __shfl_xor(p2, off, 64);
          p3 += __shfl_xor(p3, off, 64);
        }
        float s0 = ee_lds[k0] - 2.f * p0;
        float s1 = ee_lds[k1] - 2.f * p1;
        float s2 = ee_lds[k2] - 2.f * p2;
        float s3 = ee_lds[k3] - 2.f * p3;
        if (s0 < bs || (s0 == bs && k0 < bk)) { bs = s0; bk = k0; }
        if (s1 < bs || (s1 == bs && k1 < bk)) { bs = s1; bk = k1; }
        if (s2 < bs || (s2 == bs && k2 < bk)) { bs = s2; bk = k2; }
        if (s3 < bs || (s3 == bs && k3 < bk)) { bs = s3; bk = k3; }
      }
      for (; c < cnt; ++c) {
        int k = cand[tok * MAXC + c];
        float4 ev = *reinterpret_cast<const float4*>(cb + (size_t)k * 256 + lane * 4);
        float dp = zv.x * ev.x + zv.y * ev.y + zv.z * ev.z + zv.w * ev.w;
        #pragma unroll
        for (int off = 32; off; off >>= 1) dp += __shfl_xor(dp, off, 64);
        float s = ee_lds[k] - 2.f * dp;   // identical on all lanes
        if (s < bs || (s == bs && k < bk)) { bs = s; bk = k; }
      }
    }
    bkbuf[tok] = (unsigned short)bk;
  }

  // ---- phase 2: outputs + loss, 2 tokens in flight ----
  float lsum = 0.f, msum = 0.f;
  for (int it = 0; it < 16; it += 2) {
    int tokA = wv * 16 + it, tokB = tokA + 1;
    int na = n0 + tokA, nb = n0 + tokB;
    int ba = bkbuf[tokA], bb = bkbuf[tokB];
    float4 za = *reinterpret_cast<const float4*>(z + (size_t)na * 256 + lane * 4);
    float4 zb = *reinterpret_cast<const float4*>(z + (size_t)nb * 256 + lane * 4);
    float4 qa = *reinterpret_cast<const float4*>(cb + (size_t)ba * 256 + lane * 4);
    float4 qb = *reinterpret_cast<const float4*>(cb + (size_t)bb * 256 + lane * 4);
    float ma = mask[na], mb = mask[nb];
    float4 oa; oa.x = qa.x * ma; oa.y = qa.y * ma; oa.z = qa.z * ma; oa.w = qa.w * ma;
    float4 ob; ob.x = qb.x * mb; ob.y = qb.y * mb; ob.z = qb.z * mb; ob.w = qb.w * mb;
    *reinterpret_cast<float4*>(out_q + (size_t)na * 256 + lane * 4) = oa;
    *reinterpret_cast<float4*>(out_q + (size_t)nb * 256 + lane * 4) = ob;
    float dxa = za.x - qa.x, dya = za.y - qa.y, dza = za.z - qa.z, dwa = za.w - qa.w;
    float dxb = zb.x - qb.x, dyb = zb.y - qb.y, dzb = zb.z - qb.z, dwb = zb.w - qb.w;
    lsum = fmaf(ma, dxa * dxa + dya * dya + dza * dza + dwa * dwa, lsum);
    lsum = fmaf(mb, dxb * dxb + dyb * dyb + dzb * dzb + dwb * dwb, lsum);
    if (lane == 0) {
      msum += ma + mb;
      out_idx_f[na] = (ma > 0.f) ? (float)ba : 0.f;
      out_idx_f[nb] = (mb > 0.f) ? (float)bb : 0.f;
    }
  }
  #pragma unroll
  for (int off = 32; off; off >>= 1) lsum += __shfl_down(lsum, off, 64);
  if (lane == 0) { red[wv] = lsum; red[4 + wv] = msum; }
  __syncthreads();
  if (t == 0) {
    atomicAdd(&acc2[0], red[0] + red[1] + red[2] + red[3]);
    atomicAdd(&acc2[1], red[4] + red[5] + red[6] + red[7]);
    __threadfence();
    int prev = atomicAdd(done_ctr, 1);
    last = (prev == nblocks - 1);
  }
  __syncthreads();
  if (last && t == 0) {
    float s  = atomicAdd(&acc2[0], 0.0f);
    float nv = atomicAdd(&acc2[1], 0.0f);
    out_loss[0] = (nv > 0.f) ? (0.25f * s / (nv * 256.0f)) : 0.0f;
  }
}

// ---------------------------------------------------------------------------
extern "C" void kernel_launch(void* const* d_in, const int* in_sizes, int n_in,
                              void* d_out, int out_size, void* d_ws, size_t ws_size,
                              hipStream_t stream) {
  const float* z    = (const float*)d_in[0];  // (N, 256)
  const float* mask = (const float*)d_in[1];  // (N,)
  const float* cb   = (const float*)d_in[2];  // (K, 256)
  const int N = in_sizes[1];                  // 32768
  const int D = 256;
  const int K = in_sizes[2] / D;              // 1024

  float* wsf  = (float*)d_ws;
  float* acc2 = wsf;                          // 2 floats
  int*   dctr = (int*)(wsf + 2);              // 1 int
  float* ee   = wsf + 8;                      // K floats
  unsigned short* cb_bf = (unsigned short*)(ee + K);  // K*256 bf16

  float* out_q     = (float*)d_out;           // N*D
  float* out_loss  = out_q + (size_t)N * D;   // 1
  float* out_idx_f = out_loss + 1;            // N

  vq_prep<<<(K + 3) / 4, 256, 0, stream>>>(cb, cb_bf, ee, acc2, dctr, K);
  vq_main<<<N / TOK, 256, 0, stream>>>(z, cb, cb_bf, ee, mask, out_q,
                                       out_idx_f, out_loss, acc2, dctr, N / TOK, K);
}